// Round 11
// baseline (203.237 us; speedup 1.0000x reference)
//
#include <hip/hip_runtime.h>
#include <cstdint>

typedef int v4i __attribute__((ext_vector_type(4)));

#define K_DIM 4096
#define BM 256
#define BN 256
#define BK 64
#define NT (K_DIM / BK)          // 64 K-tiles
#define TILE_BYTES (BM * BK)     // 16 KiB per operand tile
#define BUFS (2 * TILE_BYTES)    // 32 KiB (A + B)
#define NBUF 4                   // 128 KiB LDS, stage t+3 during t

// ---------------------------------------------------------------------------
// Kernel 0: fused prep. blocks [0, qrows): per-row int8 quantization of x.
// blocks [qrows, ...): pack int32 weight -> int8.  (verified R7+)
// ---------------------------------------------------------------------------
__global__ __launch_bounds__(256) void prep(
    const float* __restrict__ x, int8_t* __restrict__ q,
    float* __restrict__ scales,
    const int* __restrict__ w32, int8_t* __restrict__ w8,
    int qrows, int total16)
{
    const int b = blockIdx.x;
    const int t = threadIdx.x;
    if (b < qrows) {
        const float4* xr4 = reinterpret_cast<const float4*>(x + (size_t)b * K_DIM);
        float4 v[4];
        float m = 0.0f;
#pragma unroll
        for (int i = 0; i < 4; ++i) {
            v[i] = xr4[i * 256 + t];
            m = fmaxf(m, fmaxf(fmaxf(fabsf(v[i].x), fabsf(v[i].y)),
                               fmaxf(fabsf(v[i].z), fabsf(v[i].w))));
        }
#pragma unroll
        for (int off = 32; off >= 1; off >>= 1)
            m = fmaxf(m, __shfl_xor(m, off, 64));
        __shared__ float wmax[4];
        if ((t & 63) == 0) wmax[t >> 6] = m;
        __syncthreads();
        const float am = fmaxf(fmaxf(wmax[0], wmax[1]), fmaxf(wmax[2], wmax[3]));
        const float s  = fmaxf(am / 127.0f, 1e-8f);
        if (t == 0) scales[b] = s;
        int* qi = reinterpret_cast<int*>(q + (size_t)b * K_DIM);
#pragma unroll
        for (int i = 0; i < 4; ++i) {
            const float e[4] = {v[i].x, v[i].y, v[i].z, v[i].w};
            unsigned packed = 0;
#pragma unroll
            for (int j = 0; j < 4; ++j) {
                float r = rintf(e[j] / s);
                r = fminf(fmaxf(r, -127.0f), 127.0f);
                packed |= ((unsigned)((int)r & 0xff)) << (8 * j);
            }
            qi[i * 256 + t] = (int)packed;
        }
    } else {
        const int i = (b - qrows) * 256 + t;
        if (i >= total16) return;
        const v4i* src = reinterpret_cast<const v4i*>(w32) + i * 4;
        v4i out;
#pragma unroll
        for (int j = 0; j < 4; ++j) {
            const v4i vv = src[j];
            out[j] = (vv.x & 0xff) | ((vv.y & 0xff) << 8) |
                     ((vv.z & 0xff) << 16) | ((unsigned)(vv.w & 0xff) << 24);
        }
        reinterpret_cast<v4i*>(w8)[i] = out;
    }
}

// ---------------------------------------------------------------------------
// Kernel 1: int8 GEMM. R5 geometry (256x256, BK=64, 8 waves 2Mx4N, wave
// 128x64 = 8x4 frags of mfma_i32_16x16x64_i8, verified 0-conflict swizzle,
// NBUF=4 / stage-t+3 / vmcnt(4) residency) restructured into 4 QUADRANT
// PHASES per K-tile: {reads (next phase's frags, lead-1, 2-4 b128);
// 1 GLDS chunk; s_barrier; setprio; 8 MFMA; setprio; s_barrier}.
// Small per-phase read batches + in-flight-across-barrier issue create the
// port/MFMA stagger (m201 mechanism) that the coarse R3/R5 bursts lacked.
//
// Residency (R5-verified): entering tile t: t,t+1 resident; t+2's 4 chunks
// in flight; during t stage t+3 (1 chunk/phase). Boundary vmcnt(4) retires
// t+2. bufn (=t+1) reads during t are resident-safe; stage during t writes
// buf[(t+3)&3] whose last readers (tile t-1) lgkm-retired before the
// t-1 -> t barrier.
// Register WAR (all in-order issue per wave): a1 read Q0, used Q1/Q3, next
// read next-Q0 (after Q3 MFMAs issue) OK; b23 read Q1, used Q2/Q3, next
// read next-Q1 OK; b01 used Q0/Q1, re-read Q3 OK; A-mh0 used Q0/Q2 while
// next set read Q2/Q3 -> ping-pong aA/aB (static names, rule 20).
// ---------------------------------------------------------------------------
__global__ __launch_bounds__(512, 2) void gemm_i8(
    const int8_t* __restrict__ A,   // [M][K] quantized activations
    const int8_t* __restrict__ B,   // [N][K] packed weight
    const float* __restrict__ sA,   // [M] per-row scales
    const float* __restrict__ wsc,  // [1] weight scale
    float* __restrict__ C,          // [M][N]
    int M, int N)
{
    __shared__ int8_t lds[NBUF * BUFS];   // 128 KiB

    const int t    = threadIdx.x;
    const int lane = t & 63;
    const int w    = t >> 6;
    const int wr   = w >> 2;        // 0..1 -> 128-row half
    const int wc   = w & 3;         // 0..3 -> 64-col slice
    const int l15  = lane & 15;

    // T1: XCD-aware block swizzle (nwg = 512, divisible by 8)
    const int nwg = gridDim.x;
    int bid = blockIdx.x;
    if ((nwg & 7) == 0) bid = (bid & 7) * (nwg >> 3) + (bid >> 3);
    const int ntn  = N / BN;
    const int brow = (bid / ntn) * BM;
    const int bcol = (bid % ntn) * BN;

    // ---- staging: linear LDS dest, inverse-swizzled global src (verified) --
    const int idx0 = t;
    const int idx1 = t + 512;
    const int r0 = idx0 >> 2, r1 = idx1 >> 2;
    const int c0 = (((idx0 & 3) ^ ((r0 >> 1) & 3)) << 4);
    const int c1 = (((idx1 & 3) ^ ((r1 >> 1) & 3)) << 4);
    const int8_t* gA0 = A + (size_t)(brow + r0) * K_DIM + c0;
    const int8_t* gA1 = A + (size_t)(brow + r1) * K_DIM + c1;
    const int8_t* gB0 = B + (size_t)(bcol + r0) * K_DIM + c0;
    const int8_t* gB1 = B + (size_t)(bcol + r1) * K_DIM + c1;
    const int dA0 = idx0 * 16, dA1 = idx1 * 16;
    const int dB0 = TILE_BYTES + idx0 * 16, dB1 = TILE_BYTES + idx1 * 16;

#define GLDS(gp, off) \
    __builtin_amdgcn_global_load_lds( \
        (const __attribute__((address_space(1))) void*)(gp), \
        (__attribute__((address_space(3))) void*)(lds + (off)), 16, 0, 0)

    // ---- swizzled fragment base offsets (R5-verified, 0-conflict) ----------
    const unsigned swz = ((unsigned)((lane >> 4) ^ ((l15 >> 1) & 3))) << 4;
    const unsigned vA = (unsigned)((wr * 128 + l15) * BK) + swz;
    const unsigned vB = (unsigned)(TILE_BYTES + (wc * 64 + l15) * BK) + swz;

    v4i acc[8][4];
#pragma unroll
    for (int m = 0; m < 8; ++m)
#pragma unroll
        for (int n = 0; n < 4; ++n)
            acc[m][n] = (v4i){0, 0, 0, 0};

    v4i aA[4], aB[4], a1[4], b01[2], b23[2];

    // ---- prologue: stage tiles 0,1,2; retire 0,1; pre-read Q0 operands -----
    GLDS(gA0, dA0); GLDS(gA1, dA1); GLDS(gB0, dB0); GLDS(gB1, dB1);
    GLDS(gA0 + BK, BUFS + dA0); GLDS(gA1 + BK, BUFS + dA1);
    GLDS(gB0 + BK, BUFS + dB0); GLDS(gB1 + BK, BUFS + dB1);
    GLDS(gA0 + 2 * BK, 2 * BUFS + dA0); GLDS(gA1 + 2 * BK, 2 * BUFS + dA1);
    GLDS(gB0 + 2 * BK, 2 * BUFS + dB0); GLDS(gB1 + 2 * BK, 2 * BUFS + dB1);
    asm volatile("s_waitcnt vmcnt(4)" ::: "memory");   // tiles 0,1 resident
    __builtin_amdgcn_s_barrier();
    aA[0] = *(const v4i*)(lds + vA);
    aA[1] = *(const v4i*)(lds + vA + 1024);
    aA[2] = *(const v4i*)(lds + vA + 2048);
    aA[3] = *(const v4i*)(lds + vA + 3072);
    b01[0] = *(const v4i*)(lds + vB);
    b01[1] = *(const v4i*)(lds + vB + 1024);

#define MFMA_PAIR(MB, AV, NB, BV) do { \
    acc[MB+0][NB+0] = __builtin_amdgcn_mfma_i32_16x16x64_i8(AV[0], BV[0], acc[MB+0][NB+0], 0,0,0); \
    acc[MB+0][NB+1] = __builtin_amdgcn_mfma_i32_16x16x64_i8(AV[0], BV[1], acc[MB+0][NB+1], 0,0,0); \
    acc[MB+1][NB+0] = __builtin_amdgcn_mfma_i32_16x16x64_i8(AV[1], BV[0], acc[MB+1][NB+0], 0,0,0); \
    acc[MB+1][NB+1] = __builtin_amdgcn_mfma_i32_16x16x64_i8(AV[1], BV[1], acc[MB+1][NB+1], 0,0,0); \
    acc[MB+2][NB+0] = __builtin_amdgcn_mfma_i32_16x16x64_i8(AV[2], BV[0], acc[MB+2][NB+0], 0,0,0); \
    acc[MB+2][NB+1] = __builtin_amdgcn_mfma_i32_16x16x64_i8(AV[2], BV[1], acc[MB+2][NB+1], 0,0,0); \
    acc[MB+3][NB+0] = __builtin_amdgcn_mfma_i32_16x16x64_i8(AV[3], BV[0], acc[MB+3][NB+0], 0,0,0); \
    acc[MB+3][NB+1] = __builtin_amdgcn_mfma_i32_16x16x64_i8(AV[3], BV[1], acc[MB+3][NB+1], 0,0,0); \
    } while (0)

#define BAR __builtin_amdgcn_s_barrier()
#define PRIO1 __builtin_amdgcn_s_setprio(1)
#define PRIO0 __builtin_amdgcn_s_setprio(0)

    // AC = this tile's mh0 set; AN = next tile's mh0 set (ping-pong).
#define TILE_BODY(T, AC, AN) do { \
    const int8_t* bufc = lds + cur * BUFS; \
    const int8_t* bufn = lds + ((cur + 1) & 3) * BUFS; \
    const unsigned sto = (unsigned)(((cur + 3) & 3) * BUFS); \
    const bool more = (T) + 3 < NT; \
    const bool notlast = (T) + 1 < NT; \
    const size_t ko = (size_t)((T) + 3) * BK; \
    /* -- Q0: read a1 (this tile mh1); mh0 x b01 ------------------------ */ \
    a1[0] = *(const v4i*)(bufc + vA + 4096); \
    a1[1] = *(const v4i*)(bufc + vA + 5120); \
    a1[2] = *(const v4i*)(bufc + vA + 6144); \
    a1[3] = *(const v4i*)(bufc + vA + 7168); \
    if (more) GLDS(gA0 + ko, sto + dA0); \
    BAR; PRIO1; MFMA_PAIR(0, AC, 0, b01); PRIO0; BAR; \
    /* -- Q1: read b23 (this tile); mh1 x b01 --------------------------- */ \
    b23[0] = *(const v4i*)(bufc + vB + 2048); \
    b23[1] = *(const v4i*)(bufc + vB + 3072); \
    if (more) GLDS(gA1 + ko, sto + dA1); \
    BAR; PRIO1; MFMA_PAIR(4, a1, 0, b01); PRIO0; BAR; \
    /* -- Q2: read next amh0[0,1]; mh0 x b23 ---------------------------- */ \
    if (notlast) { \
        AN[0] = *(const v4i*)(bufn + vA); \
        AN[1] = *(const v4i*)(bufn + vA + 1024); \
    } \
    if (more) GLDS(gB0 + ko, sto + dB0); \
    BAR; PRIO1; MFMA_PAIR(0, AC, 2, b23); PRIO0; BAR; \
    /* -- Q3: read next amh0[2,3] + next b01; mh1 x b23 ----------------- */ \
    if (notlast) { \
        AN[2] = *(const v4i*)(bufn + vA + 2048); \
        AN[3] = *(const v4i*)(bufn + vA + 3072); \
        b01[0] = *(const v4i*)(bufn + vB); \
        b01[1] = *(const v4i*)(bufn + vB + 1024); \
    } \
    if (more) GLDS(gB1 + ko, sto + dB1); \
    BAR; PRIO1; MFMA_PAIR(4, a1, 2, b23); PRIO0; \
    if (more)                  asm volatile("s_waitcnt vmcnt(4)" ::: "memory"); \
    else if ((T) + 2 < NT)     asm volatile("s_waitcnt vmcnt(0)" ::: "memory"); \
    if (notlast) BAR; \
    cur = (cur + 1) & 3; \
    } while (0)

    int cur = 0;
    for (int tt = 0; tt < NT; tt += 2) {
        TILE_BODY(tt,     aA, aB);
        TILE_BODY(tt + 1, aB, aA);
    }

    // ---- epilogue: C/D layout col = lane&15, row = (lane>>4)*4 + reg -------
    const float wsv = wsc[0];
#pragma unroll
    for (int m = 0; m < 8; ++m) {
        const int rbase = brow + wr * 128 + m * 16 + (lane >> 4) * 4;
        float sc[4];
#pragma unroll
        for (int j = 0; j < 4; ++j) sc[j] = sA[rbase + j] * wsv;
#pragma unroll
        for (int n = 0; n < 4; ++n) {
            const int col = bcol + wc * 64 + n * 16 + l15;
#pragma unroll
            for (int j = 0; j < 4; ++j)
                C[(size_t)(rbase + j) * N + col] = (float)acc[m][n][j] * sc[j];
        }
    }
#undef GLDS
#undef MFMA_PAIR
#undef BAR
#undef PRIO1
#undef PRIO0
#undef TILE_BODY
}

extern "C" void kernel_launch(void* const* d_in, const int* in_sizes, int n_in,
                              void* d_out, int out_size, void* d_ws, size_t ws_size,
                              hipStream_t stream) {
    const float* x      = (const float*)d_in[0];
    const int*   w32    = (const int*)d_in[1];     // int8 widened to int32
    const float* wscale = (const float*)d_in[2];
    float*       out    = (float*)d_out;

    const int M = in_sizes[0] / K_DIM;   // 8192
    const int N = in_sizes[1] / K_DIM;   // 4096

    int8_t* q      = (int8_t*)d_ws;
    float*  scales = (float*)((char*)d_ws + (size_t)M * K_DIM);
    int8_t* w8     = (int8_t*)((char*)d_ws + (size_t)M * K_DIM + (size_t)M * sizeof(float));

    const int total16 = (N * K_DIM) / 16;           // 1,048,576
    const int pblocks = (total16 + 255) / 256;      // 4096
    prep<<<M + pblocks, 256, 0, stream>>>(x, q, scales, w32, w8, M, total16);

    const int nblk = (M / BM) * (N / BN);           // 512
    gemm_i8<<<nblk, 512, 0, stream>>>(q, w8, scales, wscale, out, M, N);
}